// Round 2
// baseline (1225.728 us; speedup 1.0000x reference)
//
#include <hip/hip_runtime.h>

// Problem: B=8, S=1024, D=1024, H=16, P=64. Inputs/outputs FP32 (per reference).
// Pipeline (compute in bf16 MFMA, threshold 2e-2 permits):
//   0) convert Wq,Wk,Wv,Wo fp32 -> bf16 in ws (one memory-bound pass)
//   1) Qb = bf16(query) @ Wq_bf^T + bq   (MFMA GEMM, A converted on the fly)
//   2) Kb, Vb likewise
//   3) attention per (b,s) token, softmax over BATCH axis (axis=0 in ref)
//   4) d_out = sigmoid(O2 @ Wo_bf^T + bo)  -> fp32 output

using short8  = __attribute__((ext_vector_type(8))) short;   // 8 bf16 = 4 VGPRs
using floatx4 = __attribute__((ext_vector_type(4))) float;   // MFMA acc

__device__ __forceinline__ float bf2f(unsigned short u) {
    return __uint_as_float(((unsigned)u) << 16);
}
__device__ __forceinline__ unsigned short f2bf(float f) {   // RNE
    unsigned u = __float_as_uint(f);
    u += 0x7fffu + ((u >> 16) & 1u);
    return (unsigned short)(u >> 16);
}
// pack two fp32 -> (lo16 = trunc-bf16(f0), hi16 = trunc-bf16(f1)) in 1 v_perm
__device__ __forceinline__ unsigned pack_trunc(float f0, float f1) {
    return __builtin_amdgcn_perm(__float_as_uint(f1), __float_as_uint(f0), 0x07060302u);
}

// ---------------------------------------------------------------------------
// Weight conversion: 4 matrices of 1024x1024 fp32 -> bf16 (RNE). grid=(512,4).
// ---------------------------------------------------------------------------
__global__ __launch_bounds__(256) void convert_weights(
    const float* __restrict__ w0, const float* __restrict__ w1,
    const float* __restrict__ w2, const float* __restrict__ w3,
    unsigned short* __restrict__ dst)
{
    const float* srcs[4] = {w0, w1, w2, w3};
    const float* src = srcs[blockIdx.y];
    unsigned short* d = dst + (size_t)blockIdx.y * (1024u * 1024u);
    const size_t i = ((size_t)blockIdx.x * 256 + threadIdx.x) * 8;
    float4 a = *(const float4*)(src + i);
    float4 b = *(const float4*)(src + i + 4);
    uint4 o;
    o.x = ((unsigned)f2bf(a.y) << 16) | f2bf(a.x);
    o.y = ((unsigned)f2bf(a.w) << 16) | f2bf(a.z);
    o.z = ((unsigned)f2bf(b.y) << 16) | f2bf(b.x);
    o.w = ((unsigned)f2bf(b.w) << 16) | f2bf(b.z);
    *(uint4*)(d + i) = o;
}

// ---------------------------------------------------------------------------
// GEMM: C[m,n] = A[m,:] . W[n,:] + bias[n]
// A: 8192xK (fp32 if AF32, else bf16); W: 1024xK bf16; bias fp32.
// C: bf16 if !SIG, else fp32 with fused sigmoid.
// Block 256 = 4 waves; wave computes 16 rows x 64 cols via mfma_f32_16x16x32_bf16.
//   A frag: m = lane&15, k = quad*8 + j   (k-contiguous 16B)
//   B frag: n = lane&15, k = quad*8 + j
//   C/D:    col = lane&15, row = quad*4 + reg
// ---------------------------------------------------------------------------
template<bool AF32, bool SIG>
__global__ __launch_bounds__(256) void gemm_bt(
    const void* __restrict__ Ap,
    const unsigned short* __restrict__ W,
    const float* __restrict__ bias,
    void* __restrict__ Cp)
{
    constexpr int Kd = 1024;
    constexpr int Nd = 1024;
    const int wave = threadIdx.x >> 6;
    const int lane = threadIdx.x & 63;
    const int l15  = lane & 15;
    const int quad = lane >> 4;
    const int rowBase = blockIdx.x * 64 + wave * 16;
    const int colBase = blockIdx.y * 64;
    const int m = rowBase + l15;

    floatx4 acc[4] = {};
    const float*          ArowF = (const float*)Ap          + (size_t)m * Kd + quad * 8;
    const unsigned short* ArowB = (const unsigned short*)Ap + (size_t)m * Kd + quad * 8;

    #pragma unroll 2
    for (int kk = 0; kk < Kd; kk += 32) {
        short8 a;
        if (AF32) {
            float4 a0 = *(const float4*)(ArowF + kk);
            float4 a1 = *(const float4*)(ArowF + kk + 4);
            union { unsigned u[4]; short8 s; } cv;
            cv.u[0] = pack_trunc(a0.x, a0.y);
            cv.u[1] = pack_trunc(a0.z, a0.w);
            cv.u[2] = pack_trunc(a1.x, a1.y);
            cv.u[3] = pack_trunc(a1.z, a1.w);
            a = cv.s;
        } else {
            a = *(const short8*)(ArowB + kk);
        }
        #pragma unroll
        for (int t = 0; t < 4; ++t) {
            const int n = colBase + t * 16 + l15;
            short8 b = *(const short8*)(W + (size_t)n * Kd + kk + quad * 8);
            acc[t] = __builtin_amdgcn_mfma_f32_16x16x32_bf16(a, b, acc[t], 0, 0, 0);
        }
    }

    #pragma unroll
    for (int t = 0; t < 4; ++t) {
        const int n = colBase + t * 16 + l15;
        const float bv = bias[n];
        #pragma unroll
        for (int r = 0; r < 4; ++r) {
            const int row = rowBase + quad * 4 + r;
            float v = acc[t][r] + bv;
            if (SIG) {
                v = 1.0f / (1.0f + __expf(-v));
                ((float*)Cp)[(size_t)row * Nd + n] = v;
            } else {
                ((unsigned short*)Cp)[(size_t)row * Nd + n] = f2bf(v);
            }
        }
    }
}

// ---------------------------------------------------------------------------
// Attention. Grid = S (1024 blocks), block = 64 threads (thread = p).
// Q[b,s,p,h] = Qlin[b, s, h*64+p]  (split_heads transpose).
// scores[b,p,q] = sum_h Q[b,p,h] K[b,q,h] / 8 ; softmax over b (8 values);
// out[b,p,h] = sum_q attn[b,p,q] V[b,q,h]; write O2[b,s,h*64+p].
// K,V staged in LDS (bf16, inner dim padded to 17). Scores ~N(0,0.25) after
// scale -> exp without max subtraction is safe.
// O2 may alias Q: each O2 address is read/written only by the same thread,
// and the read precedes the write in program order.
// ---------------------------------------------------------------------------
__global__ __launch_bounds__(64) void attn_kernel(
    const unsigned short* __restrict__ Q,
    const unsigned short* __restrict__ Kt,
    const unsigned short* __restrict__ Vt,
    unsigned short* __restrict__ O2)
{
    const int s = blockIdx.x;
    const int p = threadIdx.x;   // 0..63

    __shared__ unsigned short Kl[8][64][17];
    __shared__ unsigned short Vl[8][64][17];

    for (int b = 0; b < 8; ++b) {
        const size_t base = ((size_t)b * 1024 + s) * 1024;
        #pragma unroll
        for (int h = 0; h < 16; ++h) {
            Kl[b][p][h] = Kt[base + h * 64 + p];   // coalesced 128B per h
            Vl[b][p][h] = Vt[base + h * 64 + p];
        }
    }
    __syncthreads();

    const float scale = 0.125f;   // 1/sqrt(64)

    // Pass 1: softmax denominators over the batch axis, per (p,q).
    float rden[64];
    #pragma unroll
    for (int q = 0; q < 64; ++q) rden[q] = 0.0f;

    for (int b = 0; b < 8; ++b) {
        const size_t base = ((size_t)b * 1024 + s) * 1024;
        float qf[16];
        #pragma unroll
        for (int h = 0; h < 16; ++h) qf[h] = bf2f(Q[base + h * 64 + p]);
        #pragma unroll
        for (int q = 0; q < 64; ++q) {
            float sc = 0.0f;
            #pragma unroll
            for (int h = 0; h < 16; ++h) sc += qf[h] * bf2f(Kl[b][q][h]);
            rden[q] += __expf(sc * scale);
        }
    }
    #pragma unroll
    for (int q = 0; q < 64; ++q) rden[q] = 1.0f / rden[q];

    // Pass 2: recompute scores, weight, accumulate PV, store.
    for (int b = 0; b < 8; ++b) {
        const size_t base = ((size_t)b * 1024 + s) * 1024;
        float qf[16], o[16];
        #pragma unroll
        for (int h = 0; h < 16; ++h) { qf[h] = bf2f(Q[base + h * 64 + p]); o[h] = 0.0f; }
        #pragma unroll
        for (int q = 0; q < 64; ++q) {
            float sc = 0.0f;
            #pragma unroll
            for (int h = 0; h < 16; ++h) sc += qf[h] * bf2f(Kl[b][q][h]);
            const float e = __expf(sc * scale) * rden[q];
            #pragma unroll
            for (int h = 0; h < 16; ++h) o[h] += e * bf2f(Vl[b][q][h]);
        }
        #pragma unroll
        for (int h = 0; h < 16; ++h)
            O2[base + h * 64 + p] = f2bf(o[h]);
    }
}

// ---------------------------------------------------------------------------
extern "C" void kernel_launch(void* const* d_in, const int* in_sizes, int n_in,
                              void* d_out, int out_size, void* d_ws, size_t ws_size,
                              hipStream_t stream) {
    // setup_inputs() order: query,key,value,Wq,bq,Wk,bk,Wv,bv,Wo,bo (all fp32)
    const float* query = (const float*)d_in[0];
    const float* key_  = (const float*)d_in[1];
    const float* value = (const float*)d_in[2];
    const float* Wq = (const float*)d_in[3];
    const float* bq = (const float*)d_in[4];
    const float* Wk = (const float*)d_in[5];
    const float* bk = (const float*)d_in[6];
    const float* Wv = (const float*)d_in[7];
    const float* bv = (const float*)d_in[8];
    const float* Wo = (const float*)d_in[9];
    const float* bo = (const float*)d_in[10];

    const size_t WN = (size_t)1024 * 1024;   // 1M elems per weight
    const size_t MN = (size_t)8192 * 1024;   // 8M elems per activation

    unsigned short* Wbf = (unsigned short*)d_ws;  // [Wq|Wk|Wv|Wo] bf16, 8 MB
    unsigned short* Wq_bf = Wbf;
    unsigned short* Wk_bf = Wbf + WN;
    unsigned short* Wv_bf = Wbf + 2 * WN;
    unsigned short* Wo_bf = Wbf + 3 * WN;
    unsigned short* Qb = Wbf + 4 * WN;       // 16 MB each
    unsigned short* Kb = Qb + MN;
    unsigned short* Vb = Kb + MN;
    unsigned short* O2 = Qb;                 // alias (safe, see attn_kernel)
    // total ws use: 8 + 48 = 56 MB

    convert_weights<<<dim3(512, 4), dim3(256), 0, stream>>>(Wq, Wk, Wv, Wo, Wbf);

    dim3 grid(128, 16);   // M/64 x N/64
    dim3 blk(256);
    gemm_bt<true,  false><<<grid, blk, 0, stream>>>(query, Wq_bf, bq, Qb);
    gemm_bt<true,  false><<<grid, blk, 0, stream>>>(key_,  Wk_bf, bk, Kb);
    gemm_bt<true,  false><<<grid, blk, 0, stream>>>(value, Wv_bf, bv, Vb);

    attn_kernel<<<dim3(1024), dim3(64), 0, stream>>>(Qb, Kb, Vb, O2);

    gemm_bt<false, true><<<grid, blk, 0, stream>>>(O2, Wo_bf, bo, d_out);
}

// Round 3
// 333.583 us; speedup vs baseline: 3.6744x; 3.6744x over previous
//
#include <hip/hip_runtime.h>

// B=8, S=1024, D=1024, H=16, P=64. FP32 I/O, bf16 MFMA compute.
// Pipeline: convert W -> bf16 | fused QKV GEMM (m97-style, A fp32 in LDS) |
//           batch-softmax attention (shfl butterfly) | final GEMM + sigmoid.

using short8  = __attribute__((ext_vector_type(8))) short;   // 8 bf16
using floatx4 = __attribute__((ext_vector_type(4))) float;   // MFMA acc

__device__ __forceinline__ float bf2f(unsigned short u) {
    return __uint_as_float(((unsigned)u) << 16);
}
__device__ __forceinline__ unsigned short f2bf(float f) {   // RNE
    unsigned u = __float_as_uint(f);
    u += 0x7fffu + ((u >> 16) & 1u);
    return (unsigned short)(u >> 16);
}
// two fp32 -> packed bf16 pair (truncation) in one v_perm
__device__ __forceinline__ unsigned pack_trunc(float f0, float f1) {
    return __builtin_amdgcn_perm(__float_as_uint(f1), __float_as_uint(f0), 0x07060302u);
}
// async global->LDS, 16B per lane; lds base must be wave-uniform (dest = base + lane*16)
__device__ __forceinline__ void async_ld16(const void* g, void* l) {
    __builtin_amdgcn_global_load_lds(
        (const __attribute__((address_space(1))) unsigned int*)g,
        (__attribute__((address_space(3))) unsigned int*)l, 16, 0, 0);
}

// ---------------------------------------------------------------------------
// Weight conversion: 4x 1024x1024 fp32 -> bf16 (RNE). grid=(512,4), block=256.
// ---------------------------------------------------------------------------
__global__ __launch_bounds__(256) void convert_weights(
    const float* __restrict__ w0, const float* __restrict__ w1,
    const float* __restrict__ w2, const float* __restrict__ w3,
    unsigned short* __restrict__ dst)
{
    const float* srcs[4] = {w0, w1, w2, w3};
    const float* src = srcs[blockIdx.y];
    unsigned short* d = dst + (size_t)blockIdx.y * (1024u * 1024u);
    const size_t i = ((size_t)blockIdx.x * 256 + threadIdx.x) * 8;
    float4 a = *(const float4*)(src + i);
    float4 b = *(const float4*)(src + i + 4);
    uint4 o;
    o.x = ((unsigned)f2bf(a.y) << 16) | f2bf(a.x);
    o.y = ((unsigned)f2bf(a.w) << 16) | f2bf(a.z);
    o.z = ((unsigned)f2bf(b.y) << 16) | f2bf(b.x);
    o.w = ((unsigned)f2bf(b.w) << 16) | f2bf(b.z);
    *(uint4*)(d + i) = o;
}

// ---------------------------------------------------------------------------
// 128x128-tile GEMM (m97 structure): C[m,n] = A[m,:].W[n,:] + bias[n]
// A: 8192xK (fp32 if AF32 else bf16), W: 1024xK bf16 (K-major both sides).
// Block 256 = 4 waves (2x2 of 64x64 wave-tiles), BK=32, 16 MFMA/barrier-pair.
// Staging via global_load_lds w16; k-chunks XOR-swizzled by row to cut LDS
// frag-read bank conflicts (fp32: 2-way=free, bf16: 4-way vs 8-way plain).
// grid.z selects among 3 (A,W,bias,C) tuples -> QKV fused in one dispatch.
// ---------------------------------------------------------------------------
template<bool AF32, bool SIG>
__global__ __launch_bounds__(256) void gemm128(
    const void* __restrict__ A0, const void* __restrict__ A1, const void* __restrict__ A2,
    const unsigned short* __restrict__ W0, const unsigned short* __restrict__ W1,
    const unsigned short* __restrict__ W2,
    const float* __restrict__ b0, const float* __restrict__ b1, const float* __restrict__ b2,
    void* __restrict__ C0, void* __restrict__ C1, void* __restrict__ C2)
{
    const int z = blockIdx.z;
    const void* Ap = (z == 0) ? A0 : (z == 1) ? A1 : A2;
    const unsigned short* W = (z == 0) ? W0 : (z == 1) ? W1 : W2;
    const float* bias = (z == 0) ? b0 : (z == 1) ? b1 : b2;
    void* Cp = (z == 0) ? C0 : (z == 1) ? C1 : C2;

    constexpr int Kd = 1024, Nd = 1024;
    const int t = threadIdx.x;
    const int w = t >> 6, lane = t & 63;
    const int l15 = lane & 15, quad = lane >> 4;
    const int blockM = blockIdx.x * 128;
    const int blockN = blockIdx.y * 128;
    const int wy = w >> 1, wx = w & 1;     // wave tile: rows wy*64, cols wx*64

    __shared__ unsigned short Bs[128 * 32];                    // 8 KB
    constexpr int ABYTES = AF32 ? (128 * 32 * 4) : (128 * 32 * 2);
    __shared__ __align__(16) unsigned char AsRaw[ABYTES];
    float* AsF = (float*)AsRaw;
    unsigned short* AsB = (unsigned short*)AsRaw;

    // --- staging invariants ---
    // B (bf16): rows of 32 elems = 4 chunks of 8; lane covers row l>>2, chunk slot l&3,
    //           stages global chunk (l&3)^(row&3). 2 instr/thread (j=0,1 -> +16 rows).
    const int br  = lane >> 2;                    // 0..15
    const int bg  = (lane & 3) ^ (br & 3);        // global chunk staged
    const unsigned short* Bsrc0 = W + (size_t)(blockN + w * 32 + br) * Kd + bg * 8;
    const unsigned short* Bsrc1 = Bsrc0 + (size_t)16 * Kd;
    unsigned short* Bdst0 = &Bs[(w * 2 + 0) * 512];
    unsigned short* Bdst1 = &Bs[(w * 2 + 1) * 512];

    // A fp32: rows of 32 fp32 = 8 chunks of 4; lane covers row l>>3, slot l&7,
    //         stages global chunk (l&7)^(row&7). 4 instr/thread.
    const int ar = lane >> 3;                     // 0..7
    const int ag = (lane & 7) ^ (ar & 7);
    const float* AsrcF[4];
    float* AdstF[4];
    const unsigned short* AsrcB0 = nullptr; const unsigned short* AsrcB1 = nullptr;
    unsigned short* AdstB0 = nullptr; unsigned short* AdstB1 = nullptr;
    if (AF32) {
        #pragma unroll
        for (int j = 0; j < 4; ++j) {
            AsrcF[j] = (const float*)Ap + (size_t)(blockM + w * 32 + j * 8 + ar) * Kd + ag * 4;
            AdstF[j] = AsF + (w * 4 + j) * 256;
        }
    } else {
        AsrcB0 = (const unsigned short*)Ap + (size_t)(blockM + w * 32 + br) * Kd + bg * 8;
        AsrcB1 = AsrcB0 + (size_t)16 * Kd;
        AdstB0 = &AsB[(w * 2 + 0) * 512];
        AdstB1 = &AsB[(w * 2 + 1) * 512];
    }

    floatx4 acc[4][4] = {};

    for (int k0 = 0; k0 < Kd; k0 += 32) {
        if (AF32) {
            #pragma unroll
            for (int j = 0; j < 4; ++j) async_ld16(AsrcF[j] + k0, AdstF[j]);
        } else {
            async_ld16(AsrcB0 + k0, AdstB0);
            async_ld16(AsrcB1 + k0, AdstB1);
        }
        async_ld16(Bsrc0 + k0, Bdst0);
        async_ld16(Bsrc1 + k0, Bdst1);
        __syncthreads();

        short8 af[4], bfr[4];
        #pragma unroll
        for (int mt = 0; mt < 4; ++mt) {
            const int row = wy * 64 + mt * 16 + l15;
            if (AF32) {
                const int r7 = l15 & 7;
                const float* ap = AsF + row * 32;
                float4 lo = *(const float4*)(ap + (((quad * 2 + 0) ^ r7) * 4));
                float4 hi = *(const float4*)(ap + (((quad * 2 + 1) ^ r7) * 4));
                union { unsigned u[4]; short8 s; } cv;
                cv.u[0] = pack_trunc(lo.x, lo.y);
                cv.u[1] = pack_trunc(lo.z, lo.w);
                cv.u[2] = pack_trunc(hi.x, hi.y);
                cv.u[3] = pack_trunc(hi.z, hi.w);
                af[mt] = cv.s;
            } else {
                af[mt] = *(const short8*)&AsB[row * 32 + (quad ^ (l15 & 3)) * 8];
            }
        }
        #pragma unroll
        for (int nt = 0; nt < 4; ++nt) {
            const int row = wx * 64 + nt * 16 + l15;
            bfr[nt] = *(const short8*)&Bs[row * 32 + (quad ^ (l15 & 3)) * 8];
        }
        #pragma unroll
        for (int mt = 0; mt < 4; ++mt)
            #pragma unroll
            for (int nt = 0; nt < 4; ++nt)
                acc[mt][nt] = __builtin_amdgcn_mfma_f32_16x16x32_bf16(af[mt], bfr[nt], acc[mt][nt], 0, 0, 0);
        __syncthreads();
    }

    // epilogue: C/D layout col=l15, row=quad*4+r
    #pragma unroll
    for (int nt = 0; nt < 4; ++nt) {
        const int col = blockN + wx * 64 + nt * 16 + l15;
        const float bv = bias[col];
        #pragma unroll
        for (int mt = 0; mt < 4; ++mt) {
            const int row = blockM + wy * 64 + mt * 16 + quad * 4;
            #pragma unroll
            for (int r = 0; r < 4; ++r) {
                float v = acc[mt][nt][r] + bv;
                if (SIG) {
                    v = 1.0f / (1.0f + __expf(-v));
                    ((float*)Cp)[(size_t)(row + r) * Nd + col] = v;
                } else {
                    ((unsigned short*)Cp)[(size_t)(row + r) * Nd + col] = f2bf(v);
                }
            }
        }
    }
}

// ---------------------------------------------------------------------------
// Attention. grid = S (1024), block = 512 (8 waves).
// Load phase: wave = batch b, lane = q; K/V transposed into LDS as [b][q][h],
//   q-stride 20 elems (b64-aligned), plane stride 1284 elems (bank-spread:
//   642 dwords = 2 mod 32 -> the 8 b-plane broadcasts hit disjoint banks).
// Compute: thread t -> (b = t&7, p = t>>3). Single pass over q: score (dot16),
//   exp, batch-softmax denominator via shfl_xor(1/2/4) butterfly over the b
//   lanes, then PV accumulate. No rden array -> no spills.
// O2 aliases Q: each address is read (start) and written (end) by one thread.
// ---------------------------------------------------------------------------
__device__ __forceinline__ float dot4q(const float* qf, ushort4 k) {
    return qf[0] * bf2f(k.x) + qf[1] * bf2f(k.y) + qf[2] * bf2f(k.z) + qf[3] * bf2f(k.w);
}
__device__ __forceinline__ void axpy4(float* o, float w, ushort4 v) {
    o[0] += w * bf2f(v.x); o[1] += w * bf2f(v.y); o[2] += w * bf2f(v.z); o[3] += w * bf2f(v.w);
}

__global__ __launch_bounds__(512) void attn_kernel(
    const unsigned short* __restrict__ Q,
    const unsigned short* __restrict__ Kt,
    const unsigned short* __restrict__ Vt,
    unsigned short* __restrict__ O2)
{
    constexpr int QS = 20;               // q-stride (16 used + 4 pad)
    constexpr int PB = 64 * QS + 4;      // 1284 elems per b-plane
    __shared__ unsigned short Kl[8 * PB];
    __shared__ unsigned short Vl[8 * PB];

    const int s = blockIdx.x;
    const int t = threadIdx.x;

    {   // load + transpose: wave b8, lane lq = q
        const int b8 = t >> 6, lq = t & 63;
        const unsigned short* Ks = Kt + ((size_t)b8 * 1024 + s) * 1024;
        const unsigned short* Vs = Vt + ((size_t)b8 * 1024 + s) * 1024;
        unsigned* kd = (unsigned*)&Kl[b8 * PB + lq * QS];
        unsigned* vd = (unsigned*)&Vl[b8 * PB + lq * QS];
        #pragma unroll
        for (int w2 = 0; w2 < 8; ++w2) {
            unsigned klo = Ks[(2 * w2) * 64 + lq], khi = Ks[(2 * w2 + 1) * 64 + lq];
            kd[w2] = klo | (khi << 16);
            unsigned vlo = Vs[(2 * w2) * 64 + lq], vhi = Vs[(2 * w2 + 1) * 64 + lq];
            vd[w2] = vlo | (vhi << 16);
        }
    }
    __syncthreads();

    const int b = t & 7;
    const int p = t >> 3;                // 0..63
    const size_t qbase = ((size_t)b * 1024 + s) * 1024 + p;

    float qf[16], o[16];
    #pragma unroll
    for (int h = 0; h < 16; ++h) { qf[h] = bf2f(Q[qbase + (size_t)h * 64]); o[h] = 0.0f; }

    const unsigned short* kp = &Kl[b * PB];
    const unsigned short* vp = &Vl[b * PB];

    for (int q = 0; q < 64; ++q) {
        const int off = q * QS;
        float sc = dot4q(qf + 0,  *(const ushort4*)&kp[off + 0])
                 + dot4q(qf + 4,  *(const ushort4*)&kp[off + 4])
                 + dot4q(qf + 8,  *(const ushort4*)&kp[off + 8])
                 + dot4q(qf + 12, *(const ushort4*)&kp[off + 12]);
        float e = __expf(sc * 0.125f);
        float d = e;
        d += __shfl_xor(d, 1);
        d += __shfl_xor(d, 2);
        d += __shfl_xor(d, 4);           // sum of exp over the 8 batches
        const float wgt = e * __builtin_amdgcn_rcpf(d);
        axpy4(o + 0,  wgt, *(const ushort4*)&vp[off + 0]);
        axpy4(o + 4,  wgt, *(const ushort4*)&vp[off + 4]);
        axpy4(o + 8,  wgt, *(const ushort4*)&vp[off + 8]);
        axpy4(o + 12, wgt, *(const ushort4*)&vp[off + 12]);
    }

    #pragma unroll
    for (int h = 0; h < 16; ++h)
        O2[qbase + (size_t)h * 64] = f2bf(o[h]);
}

// ---------------------------------------------------------------------------
extern "C" void kernel_launch(void* const* d_in, const int* in_sizes, int n_in,
                              void* d_out, int out_size, void* d_ws, size_t ws_size,
                              hipStream_t stream) {
    const float* query = (const float*)d_in[0];
    const float* key_  = (const float*)d_in[1];
    const float* value = (const float*)d_in[2];
    const float* Wq = (const float*)d_in[3];
    const float* bq = (const float*)d_in[4];
    const float* Wk = (const float*)d_in[5];
    const float* bk = (const float*)d_in[6];
    const float* Wv = (const float*)d_in[7];
    const float* bv = (const float*)d_in[8];
    const float* Wo = (const float*)d_in[9];
    const float* bo = (const float*)d_in[10];

    const size_t WN = (size_t)1024 * 1024;
    const size_t MN = (size_t)8192 * 1024;

    unsigned short* Wbf = (unsigned short*)d_ws;   // 8 MB bf16 weights
    unsigned short* Wq_bf = Wbf;
    unsigned short* Wk_bf = Wbf + WN;
    unsigned short* Wv_bf = Wbf + 2 * WN;
    unsigned short* Wo_bf = Wbf + 3 * WN;
    unsigned short* Qb = Wbf + 4 * WN;             // 16 MB each
    unsigned short* Kb = Qb + MN;
    unsigned short* Vb = Kb + MN;
    unsigned short* O2 = Qb;                       // alias (safe, see attn_kernel)
    // total ws: 56 MB (same footprint as the proven round-2 layout)

    convert_weights<<<dim3(512, 4), dim3(256), 0, stream>>>(Wq, Wk, Wv, Wo, Wbf);

    // fused QKV: grid.z = 3; same-A-strip blocks (ids 64 apart) share an XCD
    gemm128<true, false><<<dim3(64, 8, 3), dim3(256), 0, stream>>>(
        query, key_, value, Wq_bf, Wk_bf, Wv_bf, bq, bk, bv, Qb, Kb, Vb);

    attn_kernel<<<dim3(1024), dim3(512), 0, stream>>>(Qb, Kb, Vb, O2);

    gemm128<false, true><<<dim3(64, 8, 1), dim3(256), 0, stream>>>(
        O2, O2, O2, Wo_bf, Wo_bf, Wo_bf, bo, bo, bo, d_out, d_out, d_out);
}

// Round 4
// 329.017 us; speedup vs baseline: 3.7254x; 1.0139x over previous
//
#include <hip/hip_runtime.h>

// B=8, S=1024, D=1024, H=16, P=64. FP32 I/O, bf16 MFMA compute.
// Fast path (ws >= 104 MB): convert W + activations -> bf16 | pure-bf16 m97
//   QKV GEMM | LDS-coalesced batch-softmax attention | final GEMM + sigmoid.
// Fallback (ws >= 56 MB): fp32-A GEMM variant (round-3 proven).

using short8  = __attribute__((ext_vector_type(8))) short;   // 8 bf16
using floatx4 = __attribute__((ext_vector_type(4))) float;   // MFMA acc

__device__ __forceinline__ float bf2f(unsigned short u) {
    return __uint_as_float(((unsigned)u) << 16);
}
__device__ __forceinline__ unsigned short f2bf(float f) {   // RNE
    unsigned u = __float_as_uint(f);
    u += 0x7fffu + ((u >> 16) & 1u);
    return (unsigned short)(u >> 16);
}
__device__ __forceinline__ unsigned pack_trunc(float f0, float f1) {
    return __builtin_amdgcn_perm(__float_as_uint(f1), __float_as_uint(f0), 0x07060302u);
}
__device__ __forceinline__ void async_ld16(const void* g, void* l) {
    __builtin_amdgcn_global_load_lds(
        (const __attribute__((address_space(1))) unsigned int*)g,
        (__attribute__((address_space(3))) unsigned int*)l, 16, 0, 0);
}

// ---------------------------------------------------------------------------
// fp32 -> bf16 (RNE), 8 elems/thread. Weights: grid (512,4). Acts: grid (4096,3).
// ---------------------------------------------------------------------------
__device__ __forceinline__ void conv8(const float* src, unsigned short* d, size_t i) {
    float4 a = *(const float4*)(src + i);
    float4 b = *(const float4*)(src + i + 4);
    uint4 o;
    o.x = ((unsigned)f2bf(a.y) << 16) | f2bf(a.x);
    o.y = ((unsigned)f2bf(a.w) << 16) | f2bf(a.z);
    o.z = ((unsigned)f2bf(b.y) << 16) | f2bf(b.x);
    o.w = ((unsigned)f2bf(b.w) << 16) | f2bf(b.z);
    *(uint4*)(d + i) = o;
}

__global__ __launch_bounds__(256) void convert_weights(
    const float* __restrict__ w0, const float* __restrict__ w1,
    const float* __restrict__ w2, const float* __restrict__ w3,
    unsigned short* __restrict__ dst)
{
    const float* srcs[4] = {w0, w1, w2, w3};
    conv8(srcs[blockIdx.y], dst + (size_t)blockIdx.y * (1024u * 1024u),
          ((size_t)blockIdx.x * 256 + threadIdx.x) * 8);
}

__global__ __launch_bounds__(256) void convert_acts(
    const float* __restrict__ a0, const float* __restrict__ a1,
    const float* __restrict__ a2, unsigned short* __restrict__ dst)
{
    const float* srcs[3] = {a0, a1, a2};
    conv8(srcs[blockIdx.y], dst + (size_t)blockIdx.y * ((size_t)8192 * 1024),
          ((size_t)blockIdx.x * 256 + threadIdx.x) * 8);
}

// ---------------------------------------------------------------------------
// 128x128-tile GEMM (m97 structure): C = A.W^T + bias. BK=32, 4 waves 2x2.
// grid.z picks among 3 problem tuples (QKV fusion).
// ---------------------------------------------------------------------------
template<bool AF32, bool SIG>
__global__ __launch_bounds__(256) void gemm128(
    const void* __restrict__ A0, const void* __restrict__ A1, const void* __restrict__ A2,
    const unsigned short* __restrict__ W0, const unsigned short* __restrict__ W1,
    const unsigned short* __restrict__ W2,
    const float* __restrict__ b0, const float* __restrict__ b1, const float* __restrict__ b2,
    void* __restrict__ C0, void* __restrict__ C1, void* __restrict__ C2)
{
    const int z = blockIdx.z;
    const void* Ap = (z == 0) ? A0 : (z == 1) ? A1 : A2;
    const unsigned short* W = (z == 0) ? W0 : (z == 1) ? W1 : W2;
    const float* bias = (z == 0) ? b0 : (z == 1) ? b1 : b2;
    void* Cp = (z == 0) ? C0 : (z == 1) ? C1 : C2;

    constexpr int Kd = 1024, Nd = 1024;
    const int t = threadIdx.x;
    const int w = t >> 6, lane = t & 63;
    const int l15 = lane & 15, quad = lane >> 4;
    const int blockM = blockIdx.x * 128;
    const int blockN = blockIdx.y * 128;
    const int wy = w >> 1, wx = w & 1;

    __shared__ unsigned short Bs[128 * 32];                    // 8 KB
    constexpr int ABYTES = AF32 ? (128 * 32 * 4) : (128 * 32 * 2);
    __shared__ __align__(16) unsigned char AsRaw[ABYTES];
    float* AsF = (float*)AsRaw;
    unsigned short* AsB = (unsigned short*)AsRaw;

    // B (bf16): row l>>2, chunk slot l&3 stages global chunk (l&3)^(row&3)
    const int br  = lane >> 2;
    const int bg  = (lane & 3) ^ (br & 3);
    const unsigned short* Bsrc0 = W + (size_t)(blockN + w * 32 + br) * Kd + bg * 8;
    const unsigned short* Bsrc1 = Bsrc0 + (size_t)16 * Kd;
    unsigned short* Bdst0 = &Bs[(w * 2 + 0) * 512];
    unsigned short* Bdst1 = &Bs[(w * 2 + 1) * 512];

    const int ar = lane >> 3;
    const int ag = (lane & 7) ^ (ar & 7);
    const float* AsrcF[4];
    float* AdstF[4];
    const unsigned short* AsrcB0 = nullptr; const unsigned short* AsrcB1 = nullptr;
    unsigned short* AdstB0 = nullptr; unsigned short* AdstB1 = nullptr;
    if (AF32) {
        #pragma unroll
        for (int j = 0; j < 4; ++j) {
            AsrcF[j] = (const float*)Ap + (size_t)(blockM + w * 32 + j * 8 + ar) * Kd + ag * 4;
            AdstF[j] = AsF + (w * 4 + j) * 256;
        }
    } else {
        AsrcB0 = (const unsigned short*)Ap + (size_t)(blockM + w * 32 + br) * Kd + bg * 8;
        AsrcB1 = AsrcB0 + (size_t)16 * Kd;
        AdstB0 = &AsB[(w * 2 + 0) * 512];
        AdstB1 = &AsB[(w * 2 + 1) * 512];
    }

    floatx4 acc[4][4] = {};

    for (int k0 = 0; k0 < Kd; k0 += 32) {
        if (AF32) {
            #pragma unroll
            for (int j = 0; j < 4; ++j) async_ld16(AsrcF[j] + k0, AdstF[j]);
        } else {
            async_ld16(AsrcB0 + k0, AdstB0);
            async_ld16(AsrcB1 + k0, AdstB1);
        }
        async_ld16(Bsrc0 + k0, Bdst0);
        async_ld16(Bsrc1 + k0, Bdst1);
        __syncthreads();

        short8 af[4], bfr[4];
        #pragma unroll
        for (int mt = 0; mt < 4; ++mt) {
            const int row = wy * 64 + mt * 16 + l15;
            if (AF32) {
                const int r7 = l15 & 7;
                const float* ap = AsF + row * 32;
                float4 lo = *(const float4*)(ap + (((quad * 2 + 0) ^ r7) * 4));
                float4 hi = *(const float4*)(ap + (((quad * 2 + 1) ^ r7) * 4));
                union { unsigned u[4]; short8 s; } cv;
                cv.u[0] = pack_trunc(lo.x, lo.y);
                cv.u[1] = pack_trunc(lo.z, lo.w);
                cv.u[2] = pack_trunc(hi.x, hi.y);
                cv.u[3] = pack_trunc(hi.z, hi.w);
                af[mt] = cv.s;
            } else {
                af[mt] = *(const short8*)&AsB[row * 32 + (quad ^ (l15 & 3)) * 8];
            }
        }
        #pragma unroll
        for (int nt = 0; nt < 4; ++nt) {
            const int row = wx * 64 + nt * 16 + l15;
            bfr[nt] = *(const short8*)&Bs[row * 32 + (quad ^ (l15 & 3)) * 8];
        }
        #pragma unroll
        for (int mt = 0; mt < 4; ++mt)
            #pragma unroll
            for (int nt = 0; nt < 4; ++nt)
                acc[mt][nt] = __builtin_amdgcn_mfma_f32_16x16x32_bf16(af[mt], bfr[nt], acc[mt][nt], 0, 0, 0);
        __syncthreads();
    }

    #pragma unroll
    for (int nt = 0; nt < 4; ++nt) {
        const int col = blockN + wx * 64 + nt * 16 + l15;
        const float bv = bias[col];
        #pragma unroll
        for (int mt = 0; mt < 4; ++mt) {
            const int row = blockM + wy * 64 + mt * 16 + quad * 4;
            #pragma unroll
            for (int r = 0; r < 4; ++r) {
                float v = acc[mt][nt][r] + bv;
                if (SIG) {
                    v = 1.0f / (1.0f + __expf(-v));
                    ((float*)Cp)[(size_t)(row + r) * Nd + col] = v;
                } else {
                    ((unsigned short*)Cp)[(size_t)(row + r) * Nd + col] = f2bf(v);
                }
            }
        }
    }
}

// ---------------------------------------------------------------------------
// Attention. grid = S (1024), block = 512 (8 waves).
// Load phase (wave = b, lane = q/p): Q,K,V transposed into LDS [b][q][h],
//   q-stride 20 elems, plane stride 1284 elems. Global reads coalesced 128 B.
// Compute (thread = (b=t&7, p=t>>3)): score dot16 (K reads are b-only
//   addressed -> 8 distinct addrs on distinct banks -> broadcast, no
//   conflicts), exp, batch-softmax via shfl_xor(1/2/4), PV accumulate.
// Output: o -> LDS (each (b,p) slot touched only by its own thread ->
//   no barrier before write; one barrier before the transposed read-out),
//   then h-row coalesced global stores.
// O2 may alias Q: block s reads/writes only row s of each b-plane, Q fully
//   consumed into LDS before any O2 store (barrier-ordered within block).
// ---------------------------------------------------------------------------
__device__ __forceinline__ float dot4q(const float* qf, ushort4 k) {
    return qf[0] * bf2f(k.x) + qf[1] * bf2f(k.y) + qf[2] * bf2f(k.z) + qf[3] * bf2f(k.w);
}
__device__ __forceinline__ void axpy4(float* o, float w, ushort4 v) {
    o[0] += w * bf2f(v.x); o[1] += w * bf2f(v.y); o[2] += w * bf2f(v.z); o[3] += w * bf2f(v.w);
}

__global__ __launch_bounds__(512) void attn_kernel(
    const unsigned short* __restrict__ Q,
    const unsigned short* __restrict__ Kt,
    const unsigned short* __restrict__ Vt,
    unsigned short* __restrict__ O2)
{
    constexpr int QS = 20;               // q-stride (16 used + 4 pad)
    constexpr int PB = 64 * QS + 4;      // 1284 elems per b-plane
    __shared__ unsigned short Kl[8 * PB];
    __shared__ unsigned short Vl[8 * PB];
    __shared__ unsigned short Ql[8 * PB];   // reused for O on the way out

    const int s = blockIdx.x;
    const int t = threadIdx.x;
    const int b8 = t >> 6, lq = t & 63;

    {   // load + transpose
        const size_t gbase = ((size_t)b8 * 1024 + s) * 1024;
        const unsigned short* Ks = Kt + gbase;
        const unsigned short* Vs = Vt + gbase;
        const unsigned short* Qs = Q  + gbase;
        unsigned* kd = (unsigned*)&Kl[b8 * PB + lq * QS];
        unsigned* vd = (unsigned*)&Vl[b8 * PB + lq * QS];
        unsigned* qd = (unsigned*)&Ql[b8 * PB + lq * QS];
        #pragma unroll
        for (int w2 = 0; w2 < 8; ++w2) {
            unsigned klo = Ks[(2 * w2) * 64 + lq], khi = Ks[(2 * w2 + 1) * 64 + lq];
            kd[w2] = klo | (khi << 16);
            unsigned vlo = Vs[(2 * w2) * 64 + lq], vhi = Vs[(2 * w2 + 1) * 64 + lq];
            vd[w2] = vlo | (vhi << 16);
            unsigned qlo = Qs[(2 * w2) * 64 + lq], qhi = Qs[(2 * w2 + 1) * 64 + lq];
            qd[w2] = qlo | (qhi << 16);
        }
    }
    __syncthreads();

    const int b = t & 7;
    const int p = t >> 3;

    float qf[16], o[16];
    {
        const unsigned short* qp = &Ql[b * PB + p * QS];
        #pragma unroll
        for (int h4 = 0; h4 < 4; ++h4) {
            ushort4 qv = *(const ushort4*)&qp[h4 * 4];
            qf[h4 * 4 + 0] = bf2f(qv.x); qf[h4 * 4 + 1] = bf2f(qv.y);
            qf[h4 * 4 + 2] = bf2f(qv.z); qf[h4 * 4 + 3] = bf2f(qv.w);
        }
        #pragma unroll
        for (int h = 0; h < 16; ++h) o[h] = 0.0f;
    }

    const unsigned short* kp = &Kl[b * PB];
    const unsigned short* vp = &Vl[b * PB];

    for (int q = 0; q < 64; ++q) {
        const int off = q * QS;
        float sc = dot4q(qf + 0,  *(const ushort4*)&kp[off + 0])
                 + dot4q(qf + 4,  *(const ushort4*)&kp[off + 4])
                 + dot4q(qf + 8,  *(const ushort4*)&kp[off + 8])
                 + dot4q(qf + 12, *(const ushort4*)&kp[off + 12]);
        float e = __expf(sc * 0.125f);
        float d = e;
        d += __shfl_xor(d, 1);
        d += __shfl_xor(d, 2);
        d += __shfl_xor(d, 4);
        const float wgt = e * __builtin_amdgcn_rcpf(d);
        axpy4(o + 0,  wgt, *(const ushort4*)&vp[off + 0]);
        axpy4(o + 4,  wgt, *(const ushort4*)&vp[off + 4]);
        axpy4(o + 8,  wgt, *(const ushort4*)&vp[off + 8]);
        axpy4(o + 12, wgt, *(const ushort4*)&vp[off + 12]);
    }

    {   // o -> LDS (own slot only), then coalesced store
        unsigned* od = (unsigned*)&Ql[b * PB + p * QS];
        #pragma unroll
        for (int w2 = 0; w2 < 8; ++w2)
            od[w2] = ((unsigned)f2bf(o[2 * w2 + 1]) << 16) | f2bf(o[2 * w2]);
    }
    __syncthreads();

    {
        const size_t gbase = ((size_t)b8 * 1024 + s) * 1024;
        const unsigned* qd = (const unsigned*)&Ql[b8 * PB + lq * QS];
        #pragma unroll
        for (int w2 = 0; w2 < 8; ++w2) {
            unsigned v = qd[w2];
            O2[gbase + (2 * w2) * 64 + lq]     = (unsigned short)(v & 0xffff);
            O2[gbase + (2 * w2 + 1) * 64 + lq] = (unsigned short)(v >> 16);
        }
    }
}

// ---------------------------------------------------------------------------
extern "C" void kernel_launch(void* const* d_in, const int* in_sizes, int n_in,
                              void* d_out, int out_size, void* d_ws, size_t ws_size,
                              hipStream_t stream) {
    const float* query = (const float*)d_in[0];
    const float* key_  = (const float*)d_in[1];
    const float* value = (const float*)d_in[2];
    const float* Wq = (const float*)d_in[3];
    const float* bq = (const float*)d_in[4];
    const float* Wk = (const float*)d_in[5];
    const float* bk = (const float*)d_in[6];
    const float* Wv = (const float*)d_in[7];
    const float* bv = (const float*)d_in[8];
    const float* Wo = (const float*)d_in[9];
    const float* bo = (const float*)d_in[10];

    const size_t WN = (size_t)1024 * 1024;
    const size_t MN = (size_t)8192 * 1024;

    unsigned short* Wbf = (unsigned short*)d_ws;   // 8 MB bf16 weights
    unsigned short* Wq_bf = Wbf;
    unsigned short* Wk_bf = Wbf + WN;
    unsigned short* Wv_bf = Wbf + 2 * WN;
    unsigned short* Wo_bf = Wbf + 3 * WN;

    convert_weights<<<dim3(512, 4), dim3(256), 0, stream>>>(Wq, Wk, Wv, Wo, Wbf);

    const bool big = ws_size >= (4 * WN + 6 * MN) * sizeof(unsigned short); // 104 MB

    unsigned short* Qb; unsigned short* Kb; unsigned short* Vb;
    if (big) {
        unsigned short* abf = Wbf + 4 * WN;        // qbf|kbf|vbf, 48 MB
        Qb = abf + 3 * MN; Kb = Qb + MN; Vb = Kb + MN;
        convert_acts<<<dim3(4096, 3), dim3(256), 0, stream>>>(query, key_, value, abf);
        gemm128<false, false><<<dim3(64, 8, 3), dim3(256), 0, stream>>>(
            abf, abf + MN, abf + 2 * MN, Wq_bf, Wk_bf, Wv_bf, bq, bk, bv, Qb, Kb, Vb);
    } else {
        Qb = Wbf + 4 * WN; Kb = Qb + MN; Vb = Kb + MN;   // 56 MB total
        gemm128<true, false><<<dim3(64, 8, 3), dim3(256), 0, stream>>>(
            query, key_, value, Wq_bf, Wk_bf, Wv_bf, bq, bk, bv, Qb, Kb, Vb);
    }

    unsigned short* O2 = Qb;   // alias (safe, see attn_kernel)
    attn_kernel<<<dim3(1024), dim3(512), 0, stream>>>(Qb, Kb, Vb, O2);

    gemm128<false, true><<<dim3(64, 8, 1), dim3(256), 0, stream>>>(
        O2, O2, O2, Wo_bf, Wo_bf, Wo_bf, bo, bo, bo, d_out, d_out, d_out);
}

// Round 5
// 282.306 us; speedup vs baseline: 4.3418x; 1.1655x over previous
//
#include <hip/hip_runtime.h>

// B=8, S=1024, D=1024, H=16, P=64. FP32 I/O, bf16 MFMA compute.
// convert W (+acts) -> bf16 | m97-style QKV GEMM | MFMA batch-softmax
// attention | final GEMM + sigmoid.

using short8   = __attribute__((ext_vector_type(8))) short;    // 8 bf16
using floatx4  = __attribute__((ext_vector_type(4))) float;    // MFMA acc 16x16
using floatx16 = __attribute__((ext_vector_type(16))) float;   // MFMA acc 32x32

__device__ __forceinline__ float bf2f(unsigned short u) {
    return __uint_as_float(((unsigned)u) << 16);
}
__device__ __forceinline__ unsigned short f2bf(float f) {   // RNE
    unsigned u = __float_as_uint(f);
    u += 0x7fffu + ((u >> 16) & 1u);
    return (unsigned short)(u >> 16);
}
// two fp32 -> packed bf16 pair (truncation) in one v_perm: lo16=f0, hi16=f1
__device__ __forceinline__ unsigned pack_trunc(float f0, float f1) {
    return __builtin_amdgcn_perm(__float_as_uint(f1), __float_as_uint(f0), 0x07060302u);
}
__device__ __forceinline__ void async_ld16(const void* g, void* l) {
    __builtin_amdgcn_global_load_lds(
        (const __attribute__((address_space(1))) unsigned int*)g,
        (__attribute__((address_space(3))) unsigned int*)l, 16, 0, 0);
}

// ---------------------------------------------------------------------------
// fp32 -> bf16 (RNE) converters
// ---------------------------------------------------------------------------
__device__ __forceinline__ void conv8(const float* src, unsigned short* d, size_t i) {
    float4 a = *(const float4*)(src + i);
    float4 b = *(const float4*)(src + i + 4);
    uint4 o;
    o.x = ((unsigned)f2bf(a.y) << 16) | f2bf(a.x);
    o.y = ((unsigned)f2bf(a.w) << 16) | f2bf(a.z);
    o.z = ((unsigned)f2bf(b.y) << 16) | f2bf(b.x);
    o.w = ((unsigned)f2bf(b.w) << 16) | f2bf(b.z);
    *(uint4*)(d + i) = o;
}

__global__ __launch_bounds__(256) void convert_weights(
    const float* __restrict__ w0, const float* __restrict__ w1,
    const float* __restrict__ w2, const float* __restrict__ w3,
    unsigned short* __restrict__ dst)
{
    const float* srcs[4] = {w0, w1, w2, w3};
    conv8(srcs[blockIdx.y], dst + (size_t)blockIdx.y * (1024u * 1024u),
          ((size_t)blockIdx.x * 256 + threadIdx.x) * 8);
}

__global__ __launch_bounds__(256) void convert_acts(
    const float* __restrict__ a0, const float* __restrict__ a1,
    const float* __restrict__ a2, unsigned short* __restrict__ dst)
{
    const float* srcs[3] = {a0, a1, a2};
    conv8(srcs[blockIdx.y], dst + (size_t)blockIdx.y * ((size_t)8192 * 1024),
          ((size_t)blockIdx.x * 256 + threadIdx.x) * 8);
}

// ---------------------------------------------------------------------------
// 128x128-tile GEMM (m97 structure): C = A.W^T + bias. BK=32, 4 waves 2x2.
// grid.z picks among 3 problem tuples (QKV fusion). (unchanged from round 4)
// ---------------------------------------------------------------------------
template<bool AF32, bool SIG>
__global__ __launch_bounds__(256) void gemm128(
    const void* __restrict__ A0, const void* __restrict__ A1, const void* __restrict__ A2,
    const unsigned short* __restrict__ W0, const unsigned short* __restrict__ W1,
    const unsigned short* __restrict__ W2,
    const float* __restrict__ b0, const float* __restrict__ b1, const float* __restrict__ b2,
    void* __restrict__ C0, void* __restrict__ C1, void* __restrict__ C2)
{
    const int z = blockIdx.z;
    const void* Ap = (z == 0) ? A0 : (z == 1) ? A1 : A2;
    const unsigned short* W = (z == 0) ? W0 : (z == 1) ? W1 : W2;
    const float* bias = (z == 0) ? b0 : (z == 1) ? b1 : b2;
    void* Cp = (z == 0) ? C0 : (z == 1) ? C1 : C2;

    constexpr int Kd = 1024, Nd = 1024;
    const int t = threadIdx.x;
    const int w = t >> 6, lane = t & 63;
    const int l15 = lane & 15, quad = lane >> 4;
    const int blockM = blockIdx.x * 128;
    const int blockN = blockIdx.y * 128;
    const int wy = w >> 1, wx = w & 1;

    __shared__ unsigned short Bs[128 * 32];
    constexpr int ABYTES = AF32 ? (128 * 32 * 4) : (128 * 32 * 2);
    __shared__ __align__(16) unsigned char AsRaw[ABYTES];
    float* AsF = (float*)AsRaw;
    unsigned short* AsB = (unsigned short*)AsRaw;

    const int br  = lane >> 2;
    const int bg  = (lane & 3) ^ (br & 3);
    const unsigned short* Bsrc0 = W + (size_t)(blockN + w * 32 + br) * Kd + bg * 8;
    const unsigned short* Bsrc1 = Bsrc0 + (size_t)16 * Kd;
    unsigned short* Bdst0 = &Bs[(w * 2 + 0) * 512];
    unsigned short* Bdst1 = &Bs[(w * 2 + 1) * 512];

    const int ar = lane >> 3;
    const int ag = (lane & 7) ^ (ar & 7);
    const float* AsrcF[4];
    float* AdstF[4];
    const unsigned short* AsrcB0 = nullptr; const unsigned short* AsrcB1 = nullptr;
    unsigned short* AdstB0 = nullptr; unsigned short* AdstB1 = nullptr;
    if (AF32) {
        #pragma unroll
        for (int j = 0; j < 4; ++j) {
            AsrcF[j] = (const float*)Ap + (size_t)(blockM + w * 32 + j * 8 + ar) * Kd + ag * 4;
            AdstF[j] = AsF + (w * 4 + j) * 256;
        }
    } else {
        AsrcB0 = (const unsigned short*)Ap + (size_t)(blockM + w * 32 + br) * Kd + bg * 8;
        AsrcB1 = AsrcB0 + (size_t)16 * Kd;
        AdstB0 = &AsB[(w * 2 + 0) * 512];
        AdstB1 = &AsB[(w * 2 + 1) * 512];
    }

    floatx4 acc[4][4] = {};

    for (int k0 = 0; k0 < Kd; k0 += 32) {
        if (AF32) {
            #pragma unroll
            for (int j = 0; j < 4; ++j) async_ld16(AsrcF[j] + k0, AdstF[j]);
        } else {
            async_ld16(AsrcB0 + k0, AdstB0);
            async_ld16(AsrcB1 + k0, AdstB1);
        }
        async_ld16(Bsrc0 + k0, Bdst0);
        async_ld16(Bsrc1 + k0, Bdst1);
        __syncthreads();

        short8 af[4], bfr[4];
        #pragma unroll
        for (int mt = 0; mt < 4; ++mt) {
            const int row = wy * 64 + mt * 16 + l15;
            if (AF32) {
                const int r7 = l15 & 7;
                const float* ap = AsF + row * 32;
                float4 lo = *(const float4*)(ap + (((quad * 2 + 0) ^ r7) * 4));
                float4 hi = *(const float4*)(ap + (((quad * 2 + 1) ^ r7) * 4));
                union { unsigned u[4]; short8 s; } cv;
                cv.u[0] = pack_trunc(lo.x, lo.y);
                cv.u[1] = pack_trunc(lo.z, lo.w);
                cv.u[2] = pack_trunc(hi.x, hi.y);
                cv.u[3] = pack_trunc(hi.z, hi.w);
                af[mt] = cv.s;
            } else {
                af[mt] = *(const short8*)&AsB[row * 32 + (quad ^ (l15 & 3)) * 8];
            }
        }
        #pragma unroll
        for (int nt = 0; nt < 4; ++nt) {
            const int row = wx * 64 + nt * 16 + l15;
            bfr[nt] = *(const short8*)&Bs[row * 32 + (quad ^ (l15 & 3)) * 8];
        }
        #pragma unroll
        for (int mt = 0; mt < 4; ++mt)
            #pragma unroll
            for (int nt = 0; nt < 4; ++nt)
                acc[mt][nt] = __builtin_amdgcn_mfma_f32_16x16x32_bf16(af[mt], bfr[nt], acc[mt][nt], 0, 0, 0);
        __syncthreads();
    }

    #pragma unroll
    for (int nt = 0; nt < 4; ++nt) {
        const int col = blockN + wx * 64 + nt * 16 + l15;
        const float bv = bias[col];
        #pragma unroll
        for (int mt = 0; mt < 4; ++mt) {
            const int row = blockM + wy * 64 + mt * 16 + quad * 4;
            #pragma unroll
            for (int r = 0; r < 4; ++r) {
                float v = acc[mt][nt][r] + bv;
                if (SIG) {
                    v = 1.0f / (1.0f + __expf(-v));
                    ((float*)Cp)[(size_t)(row + r) * Nd + col] = v;
                } else {
                    ((unsigned short*)Cp)[(size_t)(row + r) * Nd + col] = f2bf(v);
                }
            }
        }
    }
}

// ---------------------------------------------------------------------------
// MFMA attention. grid = (S=1024, 2 p-halves), block = 512 (wave = b).
// Per (b,s): S[p][q] = sum_h Q[p][h] K[q][h] / 8; softmax over b (8 waves,
// via LDS); out[p][h] = sum_q attn[p][q] V[q][h].
//
// Stages (LDS, shorts; total 27648 = 55.3 KB):
//   Vt [8][16][72] @0      : V^T (h-major, q-contig) for PV B-frags
//   Kl [8][64][16] @9216   : K (q-major, h-contig) for score A-frags
//   Ql [8][32][16] @17408  : Q half (p-major, h-contig) for score B-frags
//   Sexp[8][32][72] @9216  : exp(scores) [p][q], overlays Kl+Ql after scores
//   Ol [8][16][36] @9216+b*2304 : out [h][p], overlays own Sexp plane
// Score MFMA: mfma_32x32x16_bf16, A=K (m=q), B=Q (n=p) -> C col=p,row=q:
//   reg-quads give 4 consecutive q -> b64 Sexp writes, [p][q] layout.
// Den stage: thread owns (p, 4q) x all b -> b64 reads, sum, rcp, rescale,
//   b64 writeback (exclusive ownership, no races).
// PV MFMA: mfma_16x16x32_bf16, A=weights[p][q], B=Vt[h][q]; C col=h,row=p
//   -> b64 Ol writes; coalesced dword global stores.
// O2 may alias Q: block (s,ph) reads/writes only its own disjoint 32-p
//   column range of row s; Q consumed into LDS before stores (barriers).
// ---------------------------------------------------------------------------
__global__ __launch_bounds__(512) void attn_mfma(
    const unsigned short* __restrict__ Q,
    const unsigned short* __restrict__ Kt,
    const unsigned short* __restrict__ Vt,
    unsigned short* __restrict__ O2)
{
    constexpr int VOFF = 0;        // shorts
    constexpr int UOFF = 9216;     // shorts (16B-aligned: 18432 B)
    constexpr int QOFF = UOFF + 8192;
    __shared__ __align__(16) unsigned short lds[UOFF + 18432];

    const int s  = blockIdx.x;
    const int ph = blockIdx.y;
    const int t  = threadIdx.x;
    const int w  = t >> 6;          // wave = b
    const int l  = t & 63;
    const int l15 = l & 15, l31 = l & 31, half = l >> 5, quad = l >> 4;

    const size_t gb = ((size_t)w * 1024 + s) * 1024;  // shorts

    // ---- load phase ----
    {
        // V: dword view, global row h = 32 dwords; lanes: qd=l31, h=it*2+half
        const unsigned* vg = (const unsigned*)(Vt + gb);
        unsigned* vd = (unsigned*)lds;            // Vt dword base
        #pragma unroll
        for (int it = 0; it < 8; ++it) {
            const int h = it * 2 + half;
            vd[w * 576 + h * 36 + l31] = vg[h * 32 + l31];
        }
        // K: lane = q, pack h-pairs -> Kl[q][h] (pitch 16 shorts = 8 dwords)
        const unsigned short* kg = Kt + gb;
        unsigned* kd = (unsigned*)(lds + UOFF);
        #pragma unroll
        for (int h2 = 0; h2 < 8; ++h2) {
            unsigned klo = kg[(2 * h2) * 64 + l];
            unsigned khi = kg[(2 * h2 + 1) * 64 + l];
            kd[w * 512 + l * 8 + h2] = klo | (khi << 16);
        }
        // Q: lane covers p=l31, h-groups by half; 4 iters of h-pairs
        const unsigned short* qg = Q + gb + ph * 32;
        unsigned* qd = (unsigned*)(lds + QOFF);
        #pragma unroll
        for (int it = 0; it < 4; ++it) {
            const int h = it * 4 + half * 2;
            unsigned qlo = qg[h * 64 + l31];
            unsigned qhi = qg[(h + 1) * 64 + l31];
            qd[w * 256 + l31 * 8 + it * 2 + half] = qlo | (qhi << 16);
        }
    }
    __syncthreads();

    // ---- scores: A=K (m=q), B=Q (n=p), K=16=h ----
    floatx16 sc[2];
    {
        short8 qf = *(const short8*)&lds[QOFF + w * 512 + l31 * 16 + half * 8];
        short8 kf0 = *(const short8*)&lds[UOFF + w * 1024 + l31 * 16 + half * 8];
        short8 kf1 = *(const short8*)&lds[UOFF + w * 1024 + (32 + l31) * 16 + half * 8];
        floatx16 z = {};
        sc[0] = __builtin_amdgcn_mfma_f32_32x32x16_bf16(kf0, qf, z, 0, 0, 0);
        sc[1] = __builtin_amdgcn_mfma_f32_32x32x16_bf16(kf1, qf, z, 0, 0, 0);
    }
    __syncthreads();   // K/Q region dead -> reuse as Sexp

    // ---- exp + Sexp[p][q] writes (p = l31, q from C layout) ----
    {
        unsigned short* sx = lds + UOFF + w * 2304 + l31 * 72;
        #pragma unroll
        for (int nt = 0; nt < 2; ++nt) {
            #pragma unroll
            for (int rg = 0; rg < 4; ++rg) {
                float e0 = __expf(sc[nt][4 * rg + 0] * 0.125f);
                float e1 = __expf(sc[nt][4 * rg + 1] * 0.125f);
                float e2 = __expf(sc[nt][4 * rg + 2] * 0.125f);
                float e3 = __expf(sc[nt][4 * rg + 3] * 0.125f);
                uint2 pk = { pack_trunc(e0, e1), pack_trunc(e2, e3) };
                const int q0 = nt * 32 + rg * 8 + half * 4;
                *(uint2*)&sx[q0] = pk;
            }
        }
    }
    __syncthreads();

    // ---- batch-softmax denominators: thread owns (p=t&31, q0=(t>>5)*4) ----
    {
        const int p  = t & 31;
        const int q0 = (t >> 5) * 4;
        unsigned short* base = lds + UOFF + p * 72 + q0;
        float fv[8][4];
        float den0 = 0.f, den1 = 0.f, den2 = 0.f, den3 = 0.f;
        #pragma unroll
        for (int b = 0; b < 8; ++b) {
            uint2 v = *(const uint2*)&base[b * 2304];
            fv[b][0] = bf2f((unsigned short)(v.x & 0xffff));
            fv[b][1] = bf2f((unsigned short)(v.x >> 16));
            fv[b][2] = bf2f((unsigned short)(v.y & 0xffff));
            fv[b][3] = bf2f((unsigned short)(v.y >> 16));
            den0 += fv[b][0]; den1 += fv[b][1]; den2 += fv[b][2]; den3 += fv[b][3];
        }
        const float r0 = __builtin_amdgcn_rcpf(den0);
        const float r1 = __builtin_amdgcn_rcpf(den1);
        const float r2 = __builtin_amdgcn_rcpf(den2);
        const float r3 = __builtin_amdgcn_rcpf(den3);
        #pragma unroll
        for (int b = 0; b < 8; ++b) {
            uint2 pk = { pack_trunc(fv[b][0] * r0, fv[b][1] * r1),
                         pack_trunc(fv[b][2] * r2, fv[b][3] * r3) };
            *(uint2*)&base[b * 2304] = pk;
        }
    }
    __syncthreads();

    // ---- PV: A=weights[p][q], B=Vt[h][q]; out[p][h] ----
    floatx4 o[2] = {};
    #pragma unroll
    for (int qc = 0; qc < 2; ++qc) {
        short8 vf = *(const short8*)&lds[VOFF + w * 1152 + l15 * 72 + qc * 32 + quad * 8];
        #pragma unroll
        for (int mt = 0; mt < 2; ++mt) {
            short8 wf = *(const short8*)&lds[UOFF + w * 2304 + (mt * 16 + l15) * 72 + qc * 32 + quad * 8];
            o[mt] = __builtin_amdgcn_mfma_f32_16x16x32_bf16(wf, vf, o[mt], 0, 0, 0);
        }
    }
    // Ol[h][p] b64 writes (overlays own Sexp plane rows p<8; per-b disjoint)
    {
        unsigned short* ol = lds + UOFF + w * 2304 + l15 * 36;
        #pragma unroll
        for (int mt = 0; mt < 2; ++mt) {
            uint2 pk = { pack_trunc(o[mt][0], o[mt][1]), pack_trunc(o[mt][2], o[mt][3]) };
            *(uint2*)&ol[mt * 16 + quad * 4] = pk;
        }
    }
    __syncthreads();

    // ---- coalesced store: per wave (b), 256 dwords ----
    {
        unsigned* outdw = (unsigned*)O2;
        const unsigned* ol = (const unsigned*)(lds + UOFF + w * 2304);
        const size_t gdw = ((size_t)w * 1024 + s) * 512 + ph * 16;
        #pragma unroll
        for (int i = 0; i < 4; ++i) {
            const int d = i * 64 + l;
            const int h = d >> 4, pq = d & 15;
            outdw[gdw + h * 32 + pq] = ol[h * 18 + pq];
        }
    }
}

// ---------------------------------------------------------------------------
extern "C" void kernel_launch(void* const* d_in, const int* in_sizes, int n_in,
                              void* d_out, int out_size, void* d_ws, size_t ws_size,
                              hipStream_t stream) {
    const float* query = (const float*)d_in[0];
    const float* key_  = (const float*)d_in[1];
    const float* value = (const float*)d_in[2];
    const float* Wq = (const float*)d_in[3];
    const float* bq = (const float*)d_in[4];
    const float* Wk = (const float*)d_in[5];
    const float* bk = (const float*)d_in[6];
    const float* Wv = (const float*)d_in[7];
    const float* bv = (const float*)d_in[8];
    const float* Wo = (const float*)d_in[9];
    const float* bo = (const float*)d_in[10];

    const size_t WN = (size_t)1024 * 1024;
    const size_t MN = (size_t)8192 * 1024;

    unsigned short* Wbf = (unsigned short*)d_ws;
    unsigned short* Wq_bf = Wbf;
    unsigned short* Wk_bf = Wbf + WN;
    unsigned short* Wv_bf = Wbf + 2 * WN;
    unsigned short* Wo_bf = Wbf + 3 * WN;

    convert_weights<<<dim3(512, 4), dim3(256), 0, stream>>>(Wq, Wk, Wv, Wo, Wbf);

    const bool big = ws_size >= (4 * WN + 6 * MN) * sizeof(unsigned short); // 104 MB

    unsigned short* Qb; unsigned short* Kb; unsigned short* Vb;
    if (big) {
        unsigned short* abf = Wbf + 4 * WN;
        Qb = abf + 3 * MN; Kb = Qb + MN; Vb = Kb + MN;
        convert_acts<<<dim3(4096, 3), dim3(256), 0, stream>>>(query, key_, value, abf);
        gemm128<false, false><<<dim3(64, 8, 3), dim3(256), 0, stream>>>(
            abf, abf + MN, abf + 2 * MN, Wq_bf, Wk_bf, Wv_bf, bq, bk, bv, Qb, Kb, Vb);
    } else {
        Qb = Wbf + 4 * WN; Kb = Qb + MN; Vb = Kb + MN;
        gemm128<true, false><<<dim3(64, 8, 3), dim3(256), 0, stream>>>(
            query, key_, value, Wq_bf, Wk_bf, Wv_bf, bq, bk, bv, Qb, Kb, Vb);
    }

    unsigned short* O2 = Qb;   // alias (safe, see attn_mfma)
    attn_mfma<<<dim3(1024, 2), dim3(512), 0, stream>>>(Qb, Kb, Vb, O2);

    gemm128<false, true><<<dim3(64, 8, 1), dim3(256), 0, stream>>>(
        O2, O2, O2, Wo_bf, Wo_bf, Wo_bf, bo, bo, bo, d_out, d_out, d_out);
}